// Round 11
// baseline (277.148 us; speedup 1.0000x reference)
//
#include <hip/hip_runtime.h>
#include <hip/hip_bf16.h>

// Problem constants
#define BB 4
#define LL 900
#define DMODEL 256
#define DSTATE 16
#define DINNER 512
#define DTRANK 16
#define BL (BB*LL)          // 3600
#define NC 60               // scan chunks (per (b,dir,d), stitched in LDS)
#define LC 15               // steps per chunk; NC*LC == LL

typedef __bf16 bf16x8 __attribute__((ext_vector_type(8)));
typedef __bf16 bf16x4 __attribute__((ext_vector_type(4)));
typedef float f32x4 __attribute__((ext_vector_type(4)));

__device__ __forceinline__ float silu_f(float v) { return v / (1.f + __expf(-v)); }

// ---------------------------------------------------------------------------
// One-time hi/lo split of GEMM operands (v ~= hi + lo)
// ---------------------------------------------------------------------------
#define N_HID  (BL*DMODEL)             // 921600
#define N_WIN  (2*DINNER*DMODEL)       // 262144
#define N_WXP  (48*DINNER)             // 24576
#define N_WOUT (DMODEL*2*DINNER)       // 262144
__global__ void split_inputs(const float* __restrict__ hidden, const float* __restrict__ Win,
                             const float* __restrict__ Wxp, const float* __restrict__ Wout,
                             __bf16* __restrict__ hh, __bf16* __restrict__ hl,
                             __bf16* __restrict__ wih, __bf16* __restrict__ wil,
                             __bf16* __restrict__ wxh, __bf16* __restrict__ wxl,
                             __bf16* __restrict__ woh, __bf16* __restrict__ wol)
{
    int idx = blockIdx.x * 256 + threadIdx.x;
    const float* src; __bf16 *oh, *ol; int off;
    if (idx < N_HID)                       { src = hidden; oh = hh;  ol = hl;  off = idx; }
    else if (idx < N_HID+N_WIN)            { src = Win;    oh = wih; ol = wil; off = idx - N_HID; }
    else if (idx < N_HID+N_WIN+N_WXP)      { src = Wxp;    oh = wxh; ol = wxl; off = idx - N_HID - N_WIN; }
    else if (idx < N_HID+N_WIN+N_WXP+N_WOUT){ src = Wout;  oh = woh; ol = wol; off = idx - N_HID - N_WIN - N_WXP; }
    else return;
    float v = src[off];
    __bf16 h = (__bf16)v;
    oh[off] = h;
    ol[off] = (__bf16)(v - (float)h);
}

// ---------------------------------------------------------------------------
// gemm1: xz = hidden @ W_in^T (M=3600,N=1024,K=256), fused silu epilogue.
// ---------------------------------------------------------------------------
__launch_bounds__(256)
__global__ void gemm_silu(const __bf16* __restrict__ Ah, const __bf16* __restrict__ Al,
                          const __bf16* __restrict__ Bh, const __bf16* __restrict__ Bl,
                          __bf16* __restrict__ xh, __bf16* __restrict__ xl,
                          float* __restrict__ z_silu)
{
    constexpr int WM = 3, WN = 2, K = 256, nk = K >> 5;
    constexpr int M = BL, N = 2 * DINNER;
    int wave = (blockIdx.x * 256 + threadIdx.x) >> 6;
    int ntN = N / (16 * WN);
    if (wave >= (M / (16 * WM)) * ntN) return;
    int tm = wave / ntN, tn = wave % ntN;
    int lane = threadIdx.x & 63, q = lane >> 4, r = lane & 15;

    const bf16x8* ArH[WM]; const bf16x8* ArL[WM];
    const bf16x8* BrH[WN]; const bf16x8* BrL[WN];
    #pragma unroll
    for (int mi = 0; mi < WM; ++mi) {
        size_t row = (size_t)(tm * 16 * WM + mi * 16 + r) * K;
        ArH[mi] = reinterpret_cast<const bf16x8*>(Ah + row);
        ArL[mi] = reinterpret_cast<const bf16x8*>(Al + row);
    }
    #pragma unroll
    for (int ni = 0; ni < WN; ++ni) {
        size_t row = (size_t)(tn * 16 * WN + ni * 16 + r) * K;
        BrH[ni] = reinterpret_cast<const bf16x8*>(Bh + row);
        BrL[ni] = reinterpret_cast<const bf16x8*>(Bl + row);
    }
    f32x4 acc[WM][WN];
    #pragma unroll
    for (int mi = 0; mi < WM; ++mi)
        #pragma unroll
        for (int ni = 0; ni < WN; ++ni) acc[mi][ni] = (f32x4){0.f,0.f,0.f,0.f};

    #pragma unroll
    for (int kk = 0; kk < nk; ++kk) {
        int idx = kk * 4 + q;
        bf16x8 a_h[WM], a_l[WM], b_h[WN], b_l[WN];
        #pragma unroll
        for (int mi = 0; mi < WM; ++mi) { a_h[mi] = ArH[mi][idx]; a_l[mi] = ArL[mi][idx]; }
        #pragma unroll
        for (int ni = 0; ni < WN; ++ni) { b_h[ni] = BrH[ni][idx]; b_l[ni] = BrL[ni][idx]; }
        #pragma unroll
        for (int mi = 0; mi < WM; ++mi)
            #pragma unroll
            for (int ni = 0; ni < WN; ++ni) {
                acc[mi][ni] = __builtin_amdgcn_mfma_f32_16x16x32_bf16(a_h[mi], b_h[ni], acc[mi][ni], 0, 0, 0);
                acc[mi][ni] = __builtin_amdgcn_mfma_f32_16x16x32_bf16(a_h[mi], b_l[ni], acc[mi][ni], 0, 0, 0);
                acc[mi][ni] = __builtin_amdgcn_mfma_f32_16x16x32_bf16(a_l[mi], b_h[ni], acc[mi][ni], 0, 0, 0);
            }
    }
    #pragma unroll
    for (int mi = 0; mi < WM; ++mi)
        #pragma unroll
        for (int ni = 0; ni < WN; ++ni) {
            int col = tn * 16 * WN + ni * 16 + r;
            #pragma unroll
            for (int i = 0; i < 4; ++i) {
                int row = tm * 16 * WM + mi * 16 + q * 4 + i;
                float s = silu_f(acc[mi][ni][i]);
                if (col < DINNER) {
                    __bf16 h = (__bf16)s;
                    xh[(size_t)row * DINNER + col] = h;
                    xl[(size_t)row * DINNER + col] = (__bf16)(s - (float)h);
                } else {
                    z_silu[(size_t)row * DINNER + (col - DINNER)] = s;
                }
            }
        }
}

// ---------------------------------------------------------------------------
// gemm2 + dt fused: x_dbl = x @ W_xproj^T (M=3600,N=48,K=512), KS=4 K-split
// combined in LDS, then dt = softplus(dt_r @ Wdt^T + bdt) for the 16 rows.
// ---------------------------------------------------------------------------
__launch_bounds__(256)
__global__ void gemm2_dt(const __bf16* __restrict__ Ah, const __bf16* __restrict__ Al,
                         const __bf16* __restrict__ Bh, const __bf16* __restrict__ Bl,
                         const float* __restrict__ Wdt, const float* __restrict__ bdt,
                         float* __restrict__ dtBC, float* __restrict__ dtb)
{
    constexpr int WN = 3, K = 512, KSL = 128, nk = KSL >> 5;   // 4 chunks
    __shared__ float lds[4][16 * 48];
    int tm = blockIdx.x;                       // 225 tiles (16 rows each)
    int wv = threadIdx.x >> 6;                 // ks = wave id
    int kOff = wv * KSL;
    int lane = threadIdx.x & 63, q = lane >> 4, r = lane & 15;

    const bf16x8* ArH = reinterpret_cast<const bf16x8*>(Ah + (size_t)(tm * 16 + r) * K + kOff);
    const bf16x8* ArL = reinterpret_cast<const bf16x8*>(Al + (size_t)(tm * 16 + r) * K + kOff);
    const bf16x8* BrH[WN]; const bf16x8* BrL[WN];
    #pragma unroll
    for (int ni = 0; ni < WN; ++ni) {
        size_t row = (size_t)(ni * 16 + r) * K + kOff;
        BrH[ni] = reinterpret_cast<const bf16x8*>(Bh + row);
        BrL[ni] = reinterpret_cast<const bf16x8*>(Bl + row);
    }
    f32x4 acc[WN];
    #pragma unroll
    for (int ni = 0; ni < WN; ++ni) acc[ni] = (f32x4){0.f,0.f,0.f,0.f};

    #pragma unroll
    for (int kk = 0; kk < nk; ++kk) {
        int idx = kk * 4 + q;
        bf16x8 a_h = ArH[idx], a_l = ArL[idx];
        bf16x8 b_h[WN], b_l[WN];
        #pragma unroll
        for (int ni = 0; ni < WN; ++ni) { b_h[ni] = BrH[ni][idx]; b_l[ni] = BrL[ni][idx]; }
        #pragma unroll
        for (int ni = 0; ni < WN; ++ni) {
            acc[ni] = __builtin_amdgcn_mfma_f32_16x16x32_bf16(a_h, b_h[ni], acc[ni], 0, 0, 0);
            acc[ni] = __builtin_amdgcn_mfma_f32_16x16x32_bf16(a_h, b_l[ni], acc[ni], 0, 0, 0);
            acc[ni] = __builtin_amdgcn_mfma_f32_16x16x32_bf16(a_l, b_h[ni], acc[ni], 0, 0, 0);
        }
    }
    #pragma unroll
    for (int ni = 0; ni < WN; ++ni) {
        int col = ni * 16 + r;
        #pragma unroll
        for (int i = 0; i < 4; ++i)
            lds[wv][(q * 4 + i) * 48 + col] = acc[ni][i];
    }
    __syncthreads();
    for (int e = threadIdx.x; e < 16 * 48; e += 256) {
        float s = lds[0][e] + lds[1][e] + lds[2][e] + lds[3][e];
        lds[0][e] = s;
        int row = e / 48, col = e % 48;
        dtBC[(size_t)(tm * 16 + row) * 48 + col] = s;
    }
    __syncthreads();
    for (int it = 0; it < 32; ++it) {
        int e = threadIdx.x + it * 256;        // 8192
        int row = e >> 9, d = e & 511;
        const float* wr = Wdt + (size_t)d * DTRANK;
        float s = bdt[d];
        #pragma unroll
        for (int k = 0; k < DTRANK; ++k) s = fmaf(lds[0][row * 48 + k], wr[k], s);
        dtb[(size_t)(tm * 16 + row) * DINNER + d] = (s > 15.f) ? s : __logf(1.f + __expf(s));
    }
}

// ---------------------------------------------------------------------------
// FUSED chunked scan: one kernel does pass1 + stitch (LDS) + pass3.
// Block: 256 threads = 60 chunks x 4 d-channels (240 active). Grid (128,2,4).
// Per-thread: chunk c, channel d. Phase A: run chunk from h=0, keep per-step
// prefix-sum S[] and output p0[] in REGISTERS; P=exp2(a2*Σdt), Q=h_end -> LDS.
// Phase B: 64 threads stitch the 60-chunk recurrence per (n,dl) in LDS.
// Phase C: correction p_corr(t) = Σ_n C_n(t)·exp2(a2_n·S(t))·H0_n; emit y.
// zs (z_silu) is ALREADY silu'd.
// ---------------------------------------------------------------------------
__launch_bounds__(256)
__global__ void scan_fused(const float* __restrict__ dtb,
                           const __bf16* __restrict__ xh, const __bf16* __restrict__ xl,
                           const float* __restrict__ dtBC,
                           const float* __restrict__ AlogF, const float* __restrict__ AlogB,
                           const float* __restrict__ Df, const float* __restrict__ Db,
                           const float* __restrict__ zs,
                           __bf16* __restrict__ yh, __bf16* __restrict__ yl,  // [B,L,1024]
                           float* __restrict__ partial)                       // [B,NC,1024]
{
    __shared__ float Pl[DSTATE * NC * 4];    // [n][c][dl]  3840 floats
    __shared__ float Ql[DSTATE * NC * 4];
    int b = blockIdx.z, dir = blockIdx.y;
    int tid = threadIdx.x;
    int c = tid >> 2, dl = tid & 3;          // c in [0,64), active c < NC
    int d = blockIdx.x * 4 + dl;
    const float* Alog = dir ? AlogB : AlogF;
    float a2[DSTATE];
    #pragma unroll
    for (int n = 0; n < DSTATE; ++n) a2[n] = -__expf(Alog[d * DSTATE + n]) * 1.44269504f;
    float Dd = dir ? Db[d] : Df[d];

    float S[LC], p0[LC], h[DSTATE];
    bool active = (c < NC);

    // ---- Phase A: zero-init chunk run, outputs in registers ----
    if (active) {
        #pragma unroll
        for (int n = 0; n < DSTATE; ++n) h[n] = 0.f;
        float sdt = 0.f;
        #pragma unroll
        for (int il = 0; il < LC; ++il) {
            int i = c * LC + il;
            int l = dir ? (LL - 1 - i) : i;
            size_t base = (size_t)b * LL + l;
            float dtv = dtb[base * DINNER + d];
            float u = (float)xh[base * DINNER + d] + (float)xl[base * DINNER + d];
            float du = dtv * u;
            const f32x4* Bp = reinterpret_cast<const f32x4*>(dtBC + base * 48 + DTRANK);
            f32x4 Bq[4], Cq[4];
            #pragma unroll
            for (int j = 0; j < 4; ++j) Bq[j] = Bp[j];
            #pragma unroll
            for (int j = 0; j < 4; ++j) Cq[j] = Bp[4 + j];
            sdt += dtv;
            S[il] = sdt;
            float p = 0.f;
            #pragma unroll
            for (int n = 0; n < DSTATE; ++n) {
                h[n] = fmaf(exp2f(dtv * a2[n]), h[n], du * Bq[n >> 2][n & 3]);
                p = fmaf(h[n], Cq[n >> 2][n & 3], p);
            }
            p0[il] = p + Dd * u;
        }
        #pragma unroll
        for (int n = 0; n < DSTATE; ++n) {
            Pl[(n * NC + c) * 4 + dl] = exp2f(sdt * a2[n]);
            Ql[(n * NC + c) * 4 + dl] = h[n];
        }
    }
    __syncthreads();
    // ---- Phase B: stitch per (n, dl); H0 overwrites Pl ----
    if (tid < DSTATE * 4) {
        int n = tid >> 2, dls = tid & 3;
        float H = 0.f;
        for (int c2 = 0; c2 < NC; ++c2) {
            int o = (n * NC + c2) * 4 + dls;
            float Pv = Pl[o], Qv = Ql[o];
            Pl[o] = H;
            H = fmaf(Pv, H, Qv);
        }
    }
    __syncthreads();
    // ---- Phase C: correction + emit y ----
    if (active) {
        float H0[DSTATE];
        #pragma unroll
        for (int n = 0; n < DSTATE; ++n) H0[n] = Pl[(n * NC + c) * 4 + dl];
        float ysum = 0.f;
        #pragma unroll
        for (int il = 0; il < LC; ++il) {
            int i = c * LC + il;
            int l = dir ? (LL - 1 - i) : i;
            size_t base = (size_t)b * LL + l;
            const f32x4* Cp = reinterpret_cast<const f32x4*>(dtBC + base * 48 + DTRANK + DSTATE);
            f32x4 Cq[4];
            #pragma unroll
            for (int j = 0; j < 4; ++j) Cq[j] = Cp[j];
            float pc = 0.f;
            float Sv = S[il];
            #pragma unroll
            for (int n = 0; n < DSTATE; ++n)
                pc = fmaf(H0[n] * exp2f(a2[n] * Sv), Cq[n >> 2][n & 3], pc);
            float zg = zs[base * DINNER + d];
            float yv = (p0[il] + pc) * zg;
            __bf16 hv = (__bf16)yv;
            size_t yo = base * (2 * DINNER) + dir * DINNER + d;
            yh[yo] = hv;
            yl[yo] = (__bf16)(yv - (float)hv);
            ysum += yv;
        }
        partial[((size_t)b * NC + c) * 1024 + dir * DINNER + d] = ysum;
    }
}

// mean over chunks -> ymean[b,1024]
__global__ void mean2(const float* __restrict__ partial, float* __restrict__ ymean)
{
    int i = blockIdx.x * 256 + threadIdx.x;   // 4096
    int b = i >> 10, ch = i & 1023;
    float s = 0.f;
    #pragma unroll 5
    for (int c = 0; c < NC; ++c) s += partial[((size_t)b * NC + c) * 1024 + ch];
    ymean[i] = s / (float)LL;
}

// gemv: one wave per (b,j); 4096 waves.
template<int SIG>
__global__ void gemv1024(const float* __restrict__ vin,
                         const float* __restrict__ W,
                         const float* __restrict__ bias,
                         float* __restrict__ vout)
{
    int wv = (blockIdx.x * blockDim.x + threadIdx.x) >> 6;
    int b = wv >> 10, j = wv & 1023;
    int lane = threadIdx.x & 63;
    const float* wr = W + (size_t)j * 1024;
    const float* vr = vin + (size_t)b * 1024;
    float s = 0.f;
    for (int k = lane; k < 1024; k += 64) s = fmaf(vr[k], wr[k], s);
    #pragma unroll
    for (int o = 32; o; o >>= 1) s += __shfl_xor(s, o);
    if (lane == 0) {
        s += bias[j];
        vout[wv] = SIG ? (1.f / (1.f + __expf(-s))) : s;
    }
}

// y(hi/lo) *= g[b,ch], in place, 4 elems/thread
__global__ void scale_split(__bf16* __restrict__ yh, __bf16* __restrict__ yl,
                            const float* __restrict__ g)
{
    int idx = blockIdx.x * 256 + threadIdx.x;   // BL*1024/4
    int e = idx * 4;
    int ch = e & 1023;
    int b = (e >> 10) / LL;
    bf16x4 hv = reinterpret_cast<bf16x4*>(yh)[idx];
    bf16x4 lv = reinterpret_cast<bf16x4*>(yl)[idx];
    f32x4 gv = *reinterpret_cast<const f32x4*>(g + b * 1024 + ch);
    #pragma unroll
    for (int j = 0; j < 4; ++j) {
        float v = ((float)hv[j] + (float)lv[j]) * gv[j];
        __bf16 h = (__bf16)v;
        hv[j] = h;
        lv[j] = (__bf16)(v - (float)h);
    }
    reinterpret_cast<bf16x4*>(yh)[idx] = hv;
    reinterpret_cast<bf16x4*>(yl)[idx] = lv;
}

// ---------------------------------------------------------------------------
// gemm8: out = y @ W_out^T (M=3600,N=256,K=1024), KS=2 combined in LDS.
// ---------------------------------------------------------------------------
__launch_bounds__(256)
__global__ void gemm8_comb(const __bf16* __restrict__ Ah, const __bf16* __restrict__ Al,
                           const __bf16* __restrict__ Bh, const __bf16* __restrict__ Bl,
                           float* __restrict__ out)
{
    constexpr int WM = 3, WN = 2, K = 1024, KSL = 512, nk = KSL >> 5;  // 16 chunks
    constexpr int N = DMODEL, ntN = N / (16 * WN);                      // 8
    __shared__ float lds[2][2][48 * 32];
    int wv = threadIdx.x >> 6;
    int tLoc = wv >> 1, ks = wv & 1;
    int tIdx = blockIdx.x * 2 + tLoc;          // 600 tiles
    int tm = tIdx / ntN, tn = tIdx % ntN;
    int kOff = ks * KSL;
    int lane = threadIdx.x & 63, q = lane >> 4, r = lane & 15;

    const bf16x8* ArH[WM]; const bf16x8* ArL[WM];
    const bf16x8* BrH[WN]; const bf16x8* BrL[WN];
    #pragma unroll
    for (int mi = 0; mi < WM; ++mi) {
        size_t row = (size_t)(tm * 48 + mi * 16 + r) * K + kOff;
        ArH[mi] = reinterpret_cast<const bf16x8*>(Ah + row);
        ArL[mi] = reinterpret_cast<const bf16x8*>(Al + row);
    }
    #pragma unroll
    for (int ni = 0; ni < WN; ++ni) {
        size_t row = (size_t)(tn * 32 + ni * 16 + r) * K + kOff;
        BrH[ni] = reinterpret_cast<const bf16x8*>(Bh + row);
        BrL[ni] = reinterpret_cast<const bf16x8*>(Bl + row);
    }
    f32x4 acc[WM][WN];
    #pragma unroll
    for (int mi = 0; mi < WM; ++mi)
        #pragma unroll
        for (int ni = 0; ni < WN; ++ni) acc[mi][ni] = (f32x4){0.f,0.f,0.f,0.f};

    #pragma unroll
    for (int kk = 0; kk < nk; ++kk) {
        int idx = kk * 4 + q;
        bf16x8 a_h[WM], a_l[WM], b_h[WN], b_l[WN];
        #pragma unroll
        for (int mi = 0; mi < WM; ++mi) { a_h[mi] = ArH[mi][idx]; a_l[mi] = ArL[mi][idx]; }
        #pragma unroll
        for (int ni = 0; ni < WN; ++ni) { b_h[ni] = BrH[ni][idx]; b_l[ni] = BrL[ni][idx]; }
        #pragma unroll
        for (int mi = 0; mi < WM; ++mi)
            #pragma unroll
            for (int ni = 0; ni < WN; ++ni) {
                acc[mi][ni] = __builtin_amdgcn_mfma_f32_16x16x32_bf16(a_h[mi], b_h[ni], acc[mi][ni], 0, 0, 0);
                acc[mi][ni] = __builtin_amdgcn_mfma_f32_16x16x32_bf16(a_h[mi], b_l[ni], acc[mi][ni], 0, 0, 0);
                acc[mi][ni] = __builtin_amdgcn_mfma_f32_16x16x32_bf16(a_l[mi], b_h[ni], acc[mi][ni], 0, 0, 0);
            }
    }
    #pragma unroll
    for (int mi = 0; mi < WM; ++mi)
        #pragma unroll
        for (int ni = 0; ni < WN; ++ni) {
            int col = ni * 16 + r;
            #pragma unroll
            for (int i = 0; i < 4; ++i)
                lds[tLoc][ks][(mi * 16 + q * 4 + i) * 32 + col] = acc[mi][ni][i];
        }
    __syncthreads();
    for (int e = threadIdx.x; e < 2 * 1536; e += 256) {
        int tl = (e >= 1536) ? 1 : 0;
        int idx = e - tl * 1536;
        int row = idx >> 5, col = idx & 31;
        int tg = blockIdx.x * 2 + tl;
        int gm = (tg / ntN) * 48 + row, gn = (tg % ntN) * 32 + col;
        out[(size_t)gm * N + gn] = lds[tl][0][idx] + lds[tl][1][idx];
    }
}

// ---------------------------------------------------------------------------
extern "C" void kernel_launch(void* const* d_in, const int* in_sizes, int n_in,
                              void* d_out, int out_size, void* d_ws, size_t ws_size,
                              hipStream_t stream)
{
    const float* hidden  = (const float*)d_in[0];
    const float* W_in    = (const float*)d_in[1];
    const float* W_xproj = (const float*)d_in[2];
    const float* W_dt    = (const float*)d_in[3];
    const float* b_dt    = (const float*)d_in[4];
    const float* A_log_f = (const float*)d_in[5];
    const float* A_log_b = (const float*)d_in[6];
    const float* D_f     = (const float*)d_in[7];
    const float* D_b     = (const float*)d_in[8];
    const float* W_glob  = (const float*)d_in[9];
    const float* b_glob  = (const float*)d_in[10];
    const float* W_gate  = (const float*)d_in[11];
    const float* b_gate  = (const float*)d_in[12];
    const float* W_out   = (const float*)d_in[13];
    float* out = (float*)d_out;

    // workspace (~37 MB)
    char* w = (char*)d_ws;
    __bf16* xh    = (__bf16*)w; w += (size_t)BL * DINNER * 2;
    __bf16* xl    = (__bf16*)w; w += (size_t)BL * DINNER * 2;
    float* z_silu = (float*)w;  w += (size_t)BL * DINNER * 4;
    float* dtBC   = (float*)w;  w += (size_t)BL * 48 * 4;
    float* dtb    = (float*)w;  w += (size_t)BL * DINNER * 4;
    __bf16* yh    = (__bf16*)w; w += (size_t)BL * 2 * DINNER * 2;
    __bf16* yl    = (__bf16*)w; w += (size_t)BL * 2 * DINNER * 2;
    float* partial= (float*)w;  w += (size_t)BB * NC * 1024 * 4;
    float* ymean  = (float*)w;  w += (size_t)BB * 1024 * 4;
    float* t1     = (float*)w;  w += (size_t)BB * 1024 * 4;
    float* gbuf   = (float*)w;  w += (size_t)BB * 1024 * 4;
    __bf16* hh    = (__bf16*)w; w += (size_t)N_HID * 2;
    __bf16* hl    = (__bf16*)w; w += (size_t)N_HID * 2;
    __bf16* wih   = (__bf16*)w; w += (size_t)N_WIN * 2;
    __bf16* wil   = (__bf16*)w; w += (size_t)N_WIN * 2;
    __bf16* wxh   = (__bf16*)w; w += (size_t)N_WXP * 2;
    __bf16* wxl   = (__bf16*)w; w += (size_t)N_WXP * 2;
    __bf16* woh   = (__bf16*)w; w += (size_t)N_WOUT * 2;
    __bf16* wol   = (__bf16*)w; w += (size_t)N_WOUT * 2;

    // 0) hi/lo split of hidden + weights
    {
        int tot = N_HID + N_WIN + N_WXP + N_WOUT;
        split_inputs<<<dim3((tot + 255) / 256), dim3(256), 0, stream>>>(
            hidden, W_in, W_xproj, W_out, hh, hl, wih, wil, wxh, wxl, woh, wol);
    }
    // 1) xz = hidden @ W_in^T, fused silu+split (2400 waves)
    gemm_silu<<<dim3(600), dim3(256), 0, stream>>>(hh, hl, wih, wil, xh, xl, z_silu);
    // 2) x_dbl + dt, fused (225 blocks)
    gemm2_dt<<<dim3(225), dim3(256), 0, stream>>>(xh, xl, wxh, wxl, W_dt, b_dt, dtBC, dtb);
    // 3) FUSED scan: pass1 + LDS stitch + pass3 in one kernel (1024 blocks)
    scan_fused<<<dim3(DINNER / 4, 2, BB), dim3(256), 0, stream>>>(
        dtb, xh, xl, dtBC, A_log_f, A_log_b, D_f, D_b, z_silu, yh, yl, partial);
    // 4) mean
    mean2<<<dim3(16), dim3(256), 0, stream>>>(partial, ymean);
    // 5) gating
    gemv1024<0><<<dim3(1024), dim3(256), 0, stream>>>(ymean, W_glob, b_glob, t1);
    gemv1024<1><<<dim3(1024), dim3(256), 0, stream>>>(t1, W_gate, b_gate, gbuf);
    // 6) y *= g
    scale_split<<<dim3(BL * 1024 / 4 / 256), dim3(256), 0, stream>>>(yh, yl, gbuf);
    // 7) out = y @ W_out^T, KS=2 LDS-combined (300 blocks)
    gemm8_comb<<<dim3(300), dim3(256), 0, stream>>>(yh, yl, woh, wol, out);
}